// Round 2
// 295.722 us; speedup vs baseline: 1.0122x; 1.0122x over previous
//
#include <hip/hip_runtime.h>

// ---------------------------------------------------------------------------
// LSTM (T=1, 5 layers, H=32, E=64, B=524288) + final Linear, via f16 MFMA.
//
//  * T==1, h0=c0=0  =>  w_hh* never used, f-gate never used (c = sig(i)*tanh(g)).
//  * SINGLE-PASS f16 weights (RNE). Weight-quant gate error ~2e-4 << 5.6e-3
//    absmax budget; removes the lo-correction pass (half the MFMAs + loads).
//  * 64 batch rows per wave (4 s-tiles): weight-fragment loads amortized 2x
//    further; 12 independent MFMA accumulator chains per g2-block.
//  * exp2-domain gates: prep folds -log2e (i,o rows) / -2log2e (g rows) into
//    weights+biases, so activation uses raw v_exp_f32 (exp2), no arg muls.
//  * tanh(c), c in (-1,1), via Pade[5/4]: c*(945+105z+z^2)/(945+420z+15z^2),
//    z=c^2 (err ~5e-8); denominator folded into sigmoid(o)'s rcp ->
//    act = 3 exp2 + 2 rcp total.
//  * fc fragments use col map n=4c+t4 -> 4 contiguous out cols per lane ->
//    float4 stores.
//
// MFMA 16x16x32 layouts:
//   A: lane L holds A[m = L%16][k = 8*(L/16)+j], j=0..7
//   B: lane L holds B[k = 8*(L/16)+j][n = L%16]
//   C/D: lane L reg r holds D[row = (L/16)*4 + r][col = L%16]
// ---------------------------------------------------------------------------

typedef float    f32x4 __attribute__((ext_vector_type(4)));
typedef _Float16 h16x8 __attribute__((ext_vector_type(8)));

// ws layout (bytes):
//   [0, 40960)       : 40 weight fragments, 1024 B each (64 lanes x 16 B)
//                      [0,12)  layer0: f = (kind*2+g2)*2 + kf
//                      [12,36) layers1-4: f = 12 + (l-1)*6 + kind*2+g2
//                      [36,40) fc: f = 36 + t4
//   [40960, 42880)   : float bias[5][96]  (scaled, compact i/g/o rows)
//   [42880, 43136)   : float fcb[64]

#define LOG2E   1.4426950408889634f

__device__ __forceinline__ float lstm_act(float gi, float gg, float go) {
    // gi = -i*log2e, gg = -2g*log2e, go = -o*log2e (folded into weights)
    float a  = __builtin_amdgcn_exp2f(gi);             // e^-i
    float b  = __builtin_amdgcn_exp2f(gg);             // e^-2g
    float cc = (1.0f - b) * __builtin_amdgcn_rcpf((1.0f + a) * (1.0f + b));
    float z  = cc * cc;
    float N  = __builtin_fmaf(z, z + 105.0f, 945.0f);                      // z^2+105z+945
    float D  = __builtin_fmaf(z, __builtin_fmaf(z, 15.0f, 420.0f), 945.0f);// 15z^2+420z+945
    float d  = __builtin_amdgcn_exp2f(go);             // e^-o
    return (cc * N) * __builtin_amdgcn_rcpf((1.0f + d) * D);
}

__global__ void prep_kernel(const float* __restrict__ w_ih0,
                            const float* __restrict__ w_ih_rest,
                            const float* __restrict__ b_ih,
                            const float* __restrict__ b_hh,
                            const float* __restrict__ fc_w,
                            const float* __restrict__ fc_b,
                            unsigned char* __restrict__ ws)
{
    int t = blockIdx.x * 256 + threadIdx.x;
    if (t < 40 * 64) {
        int f = t >> 6, lane = t & 63;
        int q = lane >> 4, c = lane & 15;
        int layer, ntile, kfrag;
        if (f < 12)      { layer = 0;      ntile = f >> 1;  kfrag = f & 1; }
        else if (f < 36) { int r = f - 12; layer = 1 + r / 6; ntile = r % 6; kfrag = 0; }
        else             { layer = 5;      ntile = f - 36;  kfrag = 0; }
        int kbase = kfrag * 32 + q * 8;
        const float* src;
        float scale;
        if (layer <= 4) {
            int n = ntile * 16 + c;             // compact gate row: i[0,32) g[32,64) o[64,96)
            int orig = n + (n < 32 ? 0 : 32);
            scale = (n >= 32 && n < 64) ? -2.0f * LOG2E : -LOG2E;
            src = (layer == 0) ? (w_ih0 + orig * 64 + kbase)
                               : (w_ih_rest + (((layer - 1) * 128) + orig) * 32 + kbase);
        } else {
            int n = 4 * c + ntile;              // fc col remap for float4 stores
            scale = 1.0f;
            src = fc_w + n * 32 + kbase;
        }
        h16x8 outv;
        #pragma unroll
        for (int j = 0; j < 8; j++) outv[j] = (_Float16)(src[j] * scale);
        ((h16x8*)ws)[f * 64 + lane] = outv;
    } else if (t < 40 * 64 + 480) {
        int idx = t - 40 * 64;
        int l = idx / 96, r = idx % 96;
        int orig = r + (r < 32 ? 0 : 32);
        float scale = (r >= 32 && r < 64) ? -2.0f * LOG2E : -LOG2E;
        float* bias = (float*)(ws + 40960);
        bias[idx] = (b_ih[l * 128 + orig] + b_hh[l * 128 + orig]) * scale;
    } else if (t < 40 * 64 + 480 + 64) {
        int e = t - (40 * 64 + 480);
        float* fcb = (float*)(ws + 42880);
        fcb[e] = fc_b[e];
    }
}

__global__ __launch_bounds__(256)
void lstm_mfma(const float* __restrict__ x,
               const unsigned char* __restrict__ ws,
               float* __restrict__ out)
{
    // per-wave private h buffer; row stride 40 halves (80 B = 16B-aligned)
    __shared__ __attribute__((aligned(16))) _Float16 hs[4][64][40];   // 20 KB

    const int tid  = threadIdx.x;
    const int wave = tid >> 6;
    const int lane = tid & 63;
    const int q    = lane >> 4;
    const int c    = lane & 15;

    const long batch_base = ((long)blockIdx.x * 4 + wave) * 64;

    const h16x8* wfrag = (const h16x8*)ws;
    const float* biasf = (const float*)(ws + 40960);
    const float* fcbf  = (const float*)(ws + 42880);

    // ---- x -> A-fragments, single f16 (RNE casts keep quant unbiased)
    h16x8 xh[4][2];
    #pragma unroll
    for (int s = 0; s < 4; s++) {
        const float4* xp = (const float4*)(x + (batch_base + s * 16 + c) * 64);
        #pragma unroll
        for (int kf = 0; kf < 2; kf++) {
            float4 a = xp[kf * 8 + q * 2];
            float4 b = xp[kf * 8 + q * 2 + 1];
            xh[s][kf][0] = (_Float16)a.x; xh[s][kf][1] = (_Float16)a.y;
            xh[s][kf][2] = (_Float16)a.z; xh[s][kf][3] = (_Float16)a.w;
            xh[s][kf][4] = (_Float16)b.x; xh[s][kf][5] = (_Float16)b.y;
            xh[s][kf][6] = (_Float16)b.z; xh[s][kf][7] = (_Float16)b.w;
        }
    }

    // ---- layer 0 (K=64: 2 k-frags, single pass) ----
    #pragma unroll 1
    for (int g2 = 0; g2 < 2; g2++) {
        f32x4 acc[3][4];
        #pragma unroll
        for (int kind = 0; kind < 3; kind++) {
            float bv = biasf[kind * 32 + g2 * 16 + c];
            #pragma unroll
            for (int s = 0; s < 4; s++) acc[kind][s] = (f32x4){bv, bv, bv, bv};
        }
        #pragma unroll
        for (int kind = 0; kind < 3; kind++) {
            #pragma unroll
            for (int kf = 0; kf < 2; kf++) {
                h16x8 wh = wfrag[((kind * 2 + g2) * 2 + kf) * 64 + lane];
                #pragma unroll
                for (int s = 0; s < 4; s++)
                    acc[kind][s] = __builtin_amdgcn_mfma_f32_16x16x32_f16(xh[s][kf], wh, acc[kind][s], 0, 0, 0);
            }
        }
        #pragma unroll
        for (int s = 0; s < 4; s++) {
            #pragma unroll
            for (int r = 0; r < 4; r++) {
                float hv = lstm_act(acc[0][s][r], acc[1][s][r], acc[2][s][r]);
                hs[wave][s * 16 + q * 4 + r][g2 * 16 + c] = (_Float16)hv;
            }
        }
    }

    // ---- layers 1..4 (K=32, single pass) ----
    #pragma unroll 1
    for (int l = 1; l <= 4; l++) {
        __builtin_amdgcn_wave_barrier();   // order prev writes before reads (per-wave LDS)
        h16x8 ah[4];
        #pragma unroll
        for (int s = 0; s < 4; s++)
            ah[s] = *(const h16x8*)&hs[wave][s * 16 + c][q * 8];
        __builtin_amdgcn_wave_barrier();   // order reads before this layer's writes
        #pragma unroll 1
        for (int g2 = 0; g2 < 2; g2++) {
            f32x4 acc[3][4];
            #pragma unroll
            for (int kind = 0; kind < 3; kind++) {
                float bv = biasf[l * 96 + kind * 32 + g2 * 16 + c];
                #pragma unroll
                for (int s = 0; s < 4; s++) acc[kind][s] = (f32x4){bv, bv, bv, bv};
            }
            #pragma unroll
            for (int kind = 0; kind < 3; kind++) {
                h16x8 wh = wfrag[(12 + (l - 1) * 6 + kind * 2 + g2) * 64 + lane];
                #pragma unroll
                for (int s = 0; s < 4; s++)
                    acc[kind][s] = __builtin_amdgcn_mfma_f32_16x16x32_f16(ah[s], wh, acc[kind][s], 0, 0, 0);
            }
            #pragma unroll
            for (int s = 0; s < 4; s++) {
                #pragma unroll
                for (int r = 0; r < 4; r++) {
                    float hv = lstm_act(acc[0][s][r], acc[1][s][r], acc[2][s][r]);
                    hs[wave][s * 16 + q * 4 + r][g2 * 16 + c] = (_Float16)hv;
                }
            }
        }
    }

    // ---- fc: out[m][4c+t4] ; 4 n-tiles live -> float4 stores; s sequential ----
    __builtin_amdgcn_wave_barrier();
    h16x8 fh[4];
    #pragma unroll
    for (int s = 0; s < 4; s++)
        fh[s] = *(const h16x8*)&hs[wave][s * 16 + c][q * 8];

    h16x8 w4[4];
    float bv4[4];
    #pragma unroll
    for (int t4 = 0; t4 < 4; t4++) {
        w4[t4]  = wfrag[(36 + t4) * 64 + lane];
        bv4[t4] = fcbf[4 * c + t4];
    }
    #pragma unroll
    for (int s = 0; s < 4; s++) {
        f32x4 a4[4];
        #pragma unroll
        for (int t4 = 0; t4 < 4; t4++) a4[t4] = (f32x4){bv4[t4], bv4[t4], bv4[t4], bv4[t4]};
        #pragma unroll
        for (int t4 = 0; t4 < 4; t4++)
            a4[t4] = __builtin_amdgcn_mfma_f32_16x16x32_f16(fh[s], w4[t4], a4[t4], 0, 0, 0);
        #pragma unroll
        for (int r = 0; r < 4; r++) {
            long row = batch_base + s * 16 + q * 4 + r;
            float4 o4 = {a4[0][r], a4[1][r], a4[2][r], a4[3][r]};
            *(float4*)(out + row * 64 + 4 * c) = o4;
        }
    }
}

extern "C" void kernel_launch(void* const* d_in, const int* in_sizes, int n_in,
                              void* d_out, int out_size, void* d_ws, size_t ws_size,
                              hipStream_t stream)
{
    const float* x         = (const float*)d_in[0];
    const float* w_ih0     = (const float*)d_in[1];
    // d_in[2] = w_hh0    : unused (h0 == 0)
    const float* w_ih_rest = (const float*)d_in[3];
    // d_in[4] = w_hh_rest: unused
    const float* b_ih      = (const float*)d_in[5];
    const float* b_hh      = (const float*)d_in[6];
    const float* fc_w      = (const float*)d_in[7];
    const float* fc_b      = (const float*)d_in[8];
    unsigned char* ws      = (unsigned char*)d_ws;
    float* out             = (float*)d_out;

    // d_ws is re-poisoned before every launch -> prep must run every call.
    // 40*64 + 480 + 64 = 3104 threads -> 13 blocks
    prep_kernel<<<13, 256, 0, stream>>>(w_ih0, w_ih_rest, b_ih, b_hh, fc_w, fc_b, ws);

    // 524288 batch / (4 waves * 64 rows) = 2048 blocks
    lstm_mfma<<<2048, 256, 0, stream>>>(x, ws, out);
}

// Round 3
// 268.778 us; speedup vs baseline: 1.1136x; 1.1002x over previous
//
#include <hip/hip_runtime.h>

// ---------------------------------------------------------------------------
// LSTM (T=1, 5 layers, H=32, E=64, B=524288) + final Linear, via f16 MFMA.
//
//  * T==1, h0=c0=0  =>  w_hh* never used, f-gate never used (c = sig(i)*tanh(g)).
//  * SINGLE-PASS f16 weights (RNE). Weight-quant gate error ~2e-4 << 5.6e-3
//    absmax budget.
//  * 32 rows/wave, 4096 blocks: 16 waves/SIMD of work for TLP.
//  * g2 + layer loops FULLY UNROLLED, no wave_barriers: compiler may overlap
//    act VALU of one gate-block with MFMAs of the next, and hoist all weight/
//    bias loads (L2-resident, 43 KB) above compute. Per-wave LDS RAW ordering
//    is maintained by compiler lgkmcnt waits (same __shared__ array).
//  * exp2-domain gates: prep folds -log2e (i,o rows) / -2log2e (g rows) into
//    weights+biases, so activation uses raw v_exp_f32 (exp2), no arg muls.
//  * tanh(c), c in (-1,1), via Pade[5/4]: c*(945+105z+z^2)/(945+420z+15z^2),
//    z=c^2 (err ~5e-8); denominator folded into sigmoid(o)'s rcp ->
//    act = 3 exp2 + 2 rcp total.
//  * fc fragments use col map n=4c+t4 -> 4 contiguous out cols per lane ->
//    float4 stores.
//
// MFMA 16x16x32 layouts:
//   A: lane L holds A[m = L%16][k = 8*(L/16)+j], j=0..7
//   B: lane L holds B[k = 8*(L/16)+j][n = L%16]
//   C/D: lane L reg r holds D[row = (L/16)*4 + r][col = L%16]
// ---------------------------------------------------------------------------

typedef float    f32x4 __attribute__((ext_vector_type(4)));
typedef _Float16 h16x8 __attribute__((ext_vector_type(8)));

// ws layout (bytes):
//   [0, 40960)       : 40 weight fragments, 1024 B each (64 lanes x 16 B)
//                      [0,12)  layer0: f = (kind*2+g2)*2 + kf
//                      [12,36) layers1-4: f = 12 + (l-1)*6 + kind*2+g2
//                      [36,40) fc: f = 36 + t4
//   [40960, 42880)   : float bias[5][96]  (scaled, compact i/g/o rows)
//   [42880, 43136)   : float fcb[64]

#define LOG2E   1.4426950408889634f

__device__ __forceinline__ float lstm_act(float gi, float gg, float go) {
    // gi = -i*log2e, gg = -2g*log2e, go = -o*log2e (folded into weights)
    float a  = __builtin_amdgcn_exp2f(gi);             // e^-i
    float b  = __builtin_amdgcn_exp2f(gg);             // e^-2g
    float cc = (1.0f - b) * __builtin_amdgcn_rcpf((1.0f + a) * (1.0f + b));
    float z  = cc * cc;
    float N  = __builtin_fmaf(z, z + 105.0f, 945.0f);                      // z^2+105z+945
    float D  = __builtin_fmaf(z, __builtin_fmaf(z, 15.0f, 420.0f), 945.0f);// 15z^2+420z+945
    float d  = __builtin_amdgcn_exp2f(go);             // e^-o
    return (cc * N) * __builtin_amdgcn_rcpf((1.0f + d) * D);
}

__global__ void prep_kernel(const float* __restrict__ w_ih0,
                            const float* __restrict__ w_ih_rest,
                            const float* __restrict__ b_ih,
                            const float* __restrict__ b_hh,
                            const float* __restrict__ fc_w,
                            const float* __restrict__ fc_b,
                            unsigned char* __restrict__ ws)
{
    int t = blockIdx.x * 256 + threadIdx.x;
    if (t < 40 * 64) {
        int f = t >> 6, lane = t & 63;
        int q = lane >> 4, c = lane & 15;
        int layer, ntile, kfrag;
        if (f < 12)      { layer = 0;      ntile = f >> 1;  kfrag = f & 1; }
        else if (f < 36) { int r = f - 12; layer = 1 + r / 6; ntile = r % 6; kfrag = 0; }
        else             { layer = 5;      ntile = f - 36;  kfrag = 0; }
        int kbase = kfrag * 32 + q * 8;
        const float* src;
        float scale;
        if (layer <= 4) {
            int n = ntile * 16 + c;             // compact gate row: i[0,32) g[32,64) o[64,96)
            int orig = n + (n < 32 ? 0 : 32);
            scale = (n >= 32 && n < 64) ? -2.0f * LOG2E : -LOG2E;
            src = (layer == 0) ? (w_ih0 + orig * 64 + kbase)
                               : (w_ih_rest + (((layer - 1) * 128) + orig) * 32 + kbase);
        } else {
            int n = 4 * c + ntile;              // fc col remap for float4 stores
            scale = 1.0f;
            src = fc_w + n * 32 + kbase;
        }
        h16x8 outv;
        #pragma unroll
        for (int j = 0; j < 8; j++) outv[j] = (_Float16)(src[j] * scale);
        ((h16x8*)ws)[f * 64 + lane] = outv;
    } else if (t < 40 * 64 + 480) {
        int idx = t - 40 * 64;
        int l = idx / 96, r = idx % 96;
        int orig = r + (r < 32 ? 0 : 32);
        float scale = (r >= 32 && r < 64) ? -2.0f * LOG2E : -LOG2E;
        float* bias = (float*)(ws + 40960);
        bias[idx] = (b_ih[l * 128 + orig] + b_hh[l * 128 + orig]) * scale;
    } else if (t < 40 * 64 + 480 + 64) {
        int e = t - (40 * 64 + 480);
        float* fcb = (float*)(ws + 42880);
        fcb[e] = fc_b[e];
    }
}

__global__ __launch_bounds__(256, 4)
void lstm_mfma(const float* __restrict__ x,
               const unsigned char* __restrict__ ws,
               float* __restrict__ out)
{
    // per-wave private h buffer; row stride 40 halves (80 B = 16B-aligned)
    __shared__ __attribute__((aligned(16))) _Float16 hs[4][32][40];   // 10 KB

    const int tid  = threadIdx.x;
    const int wave = tid >> 6;
    const int lane = tid & 63;
    const int q    = lane >> 4;
    const int c    = lane & 15;

    const long batch_base = ((long)blockIdx.x * 4 + wave) * 32;

    const h16x8* wfrag = (const h16x8*)ws;
    const float* biasf = (const float*)(ws + 40960);
    const float* fcbf  = (const float*)(ws + 42880);

    // ---- x -> A-fragments, single f16 (RNE casts keep quant unbiased)
    h16x8 xh[2][2];
    #pragma unroll
    for (int s = 0; s < 2; s++) {
        const float4* xp = (const float4*)(x + (batch_base + s * 16 + c) * 64);
        #pragma unroll
        for (int kf = 0; kf < 2; kf++) {
            float4 a = xp[kf * 8 + q * 2];
            float4 b = xp[kf * 8 + q * 2 + 1];
            xh[s][kf][0] = (_Float16)a.x; xh[s][kf][1] = (_Float16)a.y;
            xh[s][kf][2] = (_Float16)a.z; xh[s][kf][3] = (_Float16)a.w;
            xh[s][kf][4] = (_Float16)b.x; xh[s][kf][5] = (_Float16)b.y;
            xh[s][kf][6] = (_Float16)b.z; xh[s][kf][7] = (_Float16)b.w;
        }
    }

    // ---- layer 0 (K=64: 2 k-frags, single pass); g2 fully unrolled ----
    #pragma unroll
    for (int g2 = 0; g2 < 2; g2++) {
        f32x4 acc[3][2];
        #pragma unroll
        for (int kind = 0; kind < 3; kind++) {
            float bv = biasf[kind * 32 + g2 * 16 + c];
            #pragma unroll
            for (int s = 0; s < 2; s++) acc[kind][s] = (f32x4){bv, bv, bv, bv};
        }
        #pragma unroll
        for (int kind = 0; kind < 3; kind++) {
            #pragma unroll
            for (int kf = 0; kf < 2; kf++) {
                h16x8 wh = wfrag[((kind * 2 + g2) * 2 + kf) * 64 + lane];
                #pragma unroll
                for (int s = 0; s < 2; s++)
                    acc[kind][s] = __builtin_amdgcn_mfma_f32_16x16x32_f16(xh[s][kf], wh, acc[kind][s], 0, 0, 0);
            }
        }
        #pragma unroll
        for (int s = 0; s < 2; s++) {
            #pragma unroll
            for (int r = 0; r < 4; r++) {
                float hv = lstm_act(acc[0][s][r], acc[1][s][r], acc[2][s][r]);
                hs[wave][s * 16 + q * 4 + r][g2 * 16 + c] = (_Float16)hv;
            }
        }
    }

    // ---- layers 1..4 (K=32, single pass); fully unrolled, no barriers ----
    #pragma unroll
    for (int l = 1; l <= 4; l++) {
        h16x8 ah[2];
        #pragma unroll
        for (int s = 0; s < 2; s++)
            ah[s] = *(const h16x8*)&hs[wave][s * 16 + c][q * 8];
        #pragma unroll
        for (int g2 = 0; g2 < 2; g2++) {
            f32x4 acc[3][2];
            #pragma unroll
            for (int kind = 0; kind < 3; kind++) {
                float bv = biasf[l * 96 + kind * 32 + g2 * 16 + c];
                #pragma unroll
                for (int s = 0; s < 2; s++) acc[kind][s] = (f32x4){bv, bv, bv, bv};
            }
            #pragma unroll
            for (int kind = 0; kind < 3; kind++) {
                h16x8 wh = wfrag[(12 + (l - 1) * 6 + kind * 2 + g2) * 64 + lane];
                #pragma unroll
                for (int s = 0; s < 2; s++)
                    acc[kind][s] = __builtin_amdgcn_mfma_f32_16x16x32_f16(ah[s], wh, acc[kind][s], 0, 0, 0);
            }
            #pragma unroll
            for (int s = 0; s < 2; s++) {
                #pragma unroll
                for (int r = 0; r < 4; r++) {
                    float hv = lstm_act(acc[0][s][r], acc[1][s][r], acc[2][s][r]);
                    hs[wave][s * 16 + q * 4 + r][g2 * 16 + c] = (_Float16)hv;
                }
            }
        }
    }

    // ---- fc: out[m][4c+t4] ; 4 n-tiles live -> float4 stores ----
    h16x8 fh[2];
    #pragma unroll
    for (int s = 0; s < 2; s++)
        fh[s] = *(const h16x8*)&hs[wave][s * 16 + c][q * 8];

    h16x8 w4[4];
    float bv4[4];
    #pragma unroll
    for (int t4 = 0; t4 < 4; t4++) {
        w4[t4]  = wfrag[(36 + t4) * 64 + lane];
        bv4[t4] = fcbf[4 * c + t4];
    }
    #pragma unroll
    for (int s = 0; s < 2; s++) {
        f32x4 a4[4];
        #pragma unroll
        for (int t4 = 0; t4 < 4; t4++) a4[t4] = (f32x4){bv4[t4], bv4[t4], bv4[t4], bv4[t4]};
        #pragma unroll
        for (int t4 = 0; t4 < 4; t4++)
            a4[t4] = __builtin_amdgcn_mfma_f32_16x16x32_f16(fh[s], w4[t4], a4[t4], 0, 0, 0);
        #pragma unroll
        for (int r = 0; r < 4; r++) {
            long row = batch_base + s * 16 + q * 4 + r;
            float4 o4 = {a4[0][r], a4[1][r], a4[2][r], a4[3][r]};
            *(float4*)(out + row * 64 + 4 * c) = o4;
        }
    }
}

extern "C" void kernel_launch(void* const* d_in, const int* in_sizes, int n_in,
                              void* d_out, int out_size, void* d_ws, size_t ws_size,
                              hipStream_t stream)
{
    const float* x         = (const float*)d_in[0];
    const float* w_ih0     = (const float*)d_in[1];
    // d_in[2] = w_hh0    : unused (h0 == 0)
    const float* w_ih_rest = (const float*)d_in[3];
    // d_in[4] = w_hh_rest: unused
    const float* b_ih      = (const float*)d_in[5];
    const float* b_hh      = (const float*)d_in[6];
    const float* fc_w      = (const float*)d_in[7];
    const float* fc_b      = (const float*)d_in[8];
    unsigned char* ws      = (unsigned char*)d_ws;
    float* out             = (float*)d_out;

    // d_ws is re-poisoned before every launch -> prep must run every call.
    // 40*64 + 480 + 64 = 3104 threads -> 13 blocks
    prep_kernel<<<13, 256, 0, stream>>>(w_ih0, w_ih_rest, b_ih, b_hh, fc_w, fc_b, ws);

    // 524288 batch / (4 waves * 32 rows) = 4096 blocks
    lstm_mfma<<<4096, 256, 0, stream>>>(x, ws, out);
}